// Round 1
// baseline (403.568 us; speedup 1.0000x reference)
//
#include <hip/hip_runtime.h>
#include <hip/hip_bf16.h>
#include <cstdint>
#include <cstddef>

// B=4, S=2048, D=1024, H=16, DK=64. Device I/O dtype: FLOAT32.
// Internal compute: bf16 MFMA with f32 accumulation.
static constexpr int kB = 4, kS = 2048, kD = 1024, kH = 16, kDK = 64;
static constexpr int kM = kB * kS;

typedef __attribute__((ext_vector_type(8))) __bf16 bf16x8;
typedef __attribute__((ext_vector_type(4))) float f32x4;

#define MFMA_BF16(a, b, c) __builtin_amdgcn_mfma_f32_16x16x32_bf16((a), (b), (c), 0, 0, 0)

#define GLDS16(gp, lp)                                                        \
  __builtin_amdgcn_global_load_lds(                                           \
      (__attribute__((address_space(1))) void*)(gp),                          \
      (__attribute__((address_space(3))) void*)(lp), 16, 0, 0)

// ---------------------------------------------------------------------------
// f32 -> bf16 converters
// ---------------------------------------------------------------------------
__device__ __forceinline__ bf16x8 cvt8(const float* s, int i) {
  const float4 a = ((const float4*)s)[i * 2 + 0];
  const float4 b = ((const float4*)s)[i * 2 + 1];
  bf16x8 o;
  o[0] = (__bf16)a.x; o[1] = (__bf16)a.y; o[2] = (__bf16)a.z; o[3] = (__bf16)a.w;
  o[4] = (__bf16)b.x; o[5] = (__bf16)b.y; o[6] = (__bf16)b.z; o[7] = (__bf16)b.w;
  return o;
}

__global__ __launch_bounds__(256) void cvt_f32_bf16(
    const float* __restrict__ src, __bf16* __restrict__ dst, int n8) {
  const int i = blockIdx.x * 256 + threadIdx.x;
  if (i >= n8) return;
  ((bf16x8*)dst)[i] = cvt8(src, i);
}

// three activations in one launch: 4096 blocks per tensor
__global__ __launch_bounds__(256) void cvt_act3(
    const float* __restrict__ a, const float* __restrict__ b,
    const float* __restrict__ c, __bf16* __restrict__ da,
    __bf16* __restrict__ db, __bf16* __restrict__ dc) {
  const int seg = blockIdx.x >> 12;
  const int i = (blockIdx.x & 4095) * 256 + threadIdx.x;
  const float* s = seg == 0 ? a : seg == 1 ? b : c;
  __bf16* d = seg == 0 ? da : seg == 1 ? db : dc;
  ((bf16x8*)d)[i] = cvt8(s, i);
}

// four weights in one launch: 512 blocks per tensor
__global__ __launch_bounds__(256) void cvt_w4(
    const float* __restrict__ a, const float* __restrict__ b,
    const float* __restrict__ c, const float* __restrict__ d,
    __bf16* __restrict__ da, __bf16* __restrict__ db,
    __bf16* __restrict__ dc, __bf16* __restrict__ dd) {
  const int seg = blockIdx.x >> 9;
  const int i = (blockIdx.x & 511) * 256 + threadIdx.x;
  const float* s = seg == 0 ? a : seg == 1 ? b : seg == 2 ? c : d;
  __bf16* o = seg == 0 ? da : seg == 1 ? db : seg == 2 ? dc : dd;
  ((bf16x8*)o)[i] = cvt8(s, i);
}

// ---------------------------------------------------------------------------
// Legacy 128x128 GEMM core (kept for gemm_one / fallback path).
// ---------------------------------------------------------------------------
template <typename OutT>
__device__ __forceinline__ void gemm_core(
    const __bf16* __restrict__ A, const __bf16* __restrict__ W,
    const float* __restrict__ bias, OutT* __restrict__ out, int mode, int bid,
    __bf16* As, __bf16* Ws) {
  const int tid = threadIdx.x;
  const int wave = tid >> 6, lane = tid & 63;
  const int col = lane & 15, quad = lane >> 4;
  const int m0 = (bid & 63) * 128;
  const int n0 = (bid >> 6) * 128;
  const int wr = (wave & 1) * 64, wc = (wave >> 1) * 64;

  f32x4 acc[4][4] = {};

  int srow[4], sgo[4];
#pragma unroll
  for (int i = 0; i < 4; ++i) {
    const int s = i * 256 + tid;
    srow[i] = s >> 3;
    sgo[i] = (((s & 7) ^ ((s >> 3) & 7))) * 8;
  }
  const int g0 = ((quad) ^ (col & 7)) * 16;
  const int g1 = ((quad + 4) ^ (col & 7)) * 16;

  for (int k0 = 0; k0 < 1024; k0 += 64) {
#pragma unroll
    for (int i = 0; i < 4; ++i) {
      GLDS16(A + (size_t)(m0 + srow[i]) * 1024 + k0 + sgo[i],
             (char*)As + i * 4096 + wave * 1024);
      GLDS16(W + (size_t)(n0 + srow[i]) * 1024 + k0 + sgo[i],
             (char*)Ws + i * 4096 + wave * 1024);
    }
    __syncthreads();
#pragma unroll
    for (int h = 0; h < 2; ++h) {
      const int go = h ? g1 : g0;
      bf16x8 af[4], wf[4];
#pragma unroll
      for (int t = 0; t < 4; ++t) {
        af[t] = *(const bf16x8*)((const char*)As + (wr + t * 16 + col) * 128 + go);
        wf[t] = *(const bf16x8*)((const char*)Ws + (wc + t * 16 + col) * 128 + go);
      }
#pragma unroll
      for (int rt = 0; rt < 4; ++rt)
#pragma unroll
        for (int ct = 0; ct < 4; ++ct)
          acc[rt][ct] = MFMA_BF16(af[rt], wf[ct], acc[rt][ct]);
    }
    __syncthreads();
  }

#pragma unroll
  for (int ct = 0; ct < 4; ++ct) {
    const int n = n0 + wc + ct * 16 + col;
    const float bb = bias[n];
#pragma unroll
    for (int rt = 0; rt < 4; ++rt) {
#pragma unroll
      for (int r = 0; r < 4; ++r) {
        const int m = m0 + wr + rt * 16 + quad * 4 + r;
        const float v = acc[rt][ct][r] + bb;
        size_t idx;
        if (mode == 0) {
          idx = (size_t)m * 1024 + n;
        } else {
          const int b = m >> 11, s = m & 2047;
          const int h = n >> 6, dk = n & 63;
          if (mode == 1)
            idx = ((size_t)(b * 16 + h) * 2048 + s) * 64 + dk;
          else
            idx = ((size_t)(b * 16 + h) * 64 + dk) * 2048 + s;
        }
        out[idx] = (OutT)v;
      }
    }
  }
}

template <int MODE, typename OutT>
__global__ __launch_bounds__(256) void gemm_one(
    const __bf16* __restrict__ A, const __bf16* __restrict__ W,
    const float* __restrict__ bias, OutT* __restrict__ out) {
  __shared__ __align__(16) __bf16 As[128 * 64];
  __shared__ __align__(16) __bf16 Ws[128 * 64];
  gemm_core<OutT>(A, W, bias, out, MODE, blockIdx.x, As, Ws);
}

// ---------------------------------------------------------------------------
// QKV projections: 256x256 tile, BK=64, 8 waves, 8-phase-style schedule with
// counted vmcnt (T3+T4) + setprio around MFMA clusters (T5).
//
// Wave (wm=wave>>2, wn=wave&3) owns rows {wm*64..+63} U {128+wm*64..+63} and
// cols {wn*32..+31} U {128+wn*32..+31}: quadrant (qm,qn) of the per-wave acc
// maps 1:1 to staged half-tiles (A-half qm, B-half qn), so each phase reads
// exactly one A-half + one B-half across ALL waves.
//
// Per K-tile t (buf = t&1), 4 phases; stage slots (one 128x64 half each):
//   ph0 reads A0,B0; stages buf^1.A1 <- tile t+1
//   ph1 reads A0,B1; stages buf^1.B1 <- tile t+1
//   ph2 reads A1,B0; stages buf.A0   <- tile t+2
//   ph3 reads A1,B1; stages buf.B0   <- tile t+2; s_waitcnt vmcnt(4)
// WAR: each stage lands in a region whose last reader finished >=1 barrier
// earlier. RAW: the ph3 vmcnt(4) (2 half-tiles in flight) forces everything
// the next 4 phases read; vmcnt(0) only entering the last K-tile.
// LDS swizzle: same involution granule-XOR as gemm_core (bank-conflict-free,
// measured 0 on this kernel family).
// ---------------------------------------------------------------------------
#define READQ(B_, QM_, QN_)                                                   \
  do {                                                                        \
    const char* Ab_ = (const char*)As8 + ((B_) * 2 + (QM_)) * 16384 + rowA;   \
    const char* Bb_ = (const char*)Bs8 + ((B_) * 2 + (QN_)) * 16384 + rowB;   \
    _Pragma("unroll") for (int mi = 0; mi < 4; ++mi) {                        \
      af[mi][0] = *(const bf16x8*)(Ab_ + mi * 2048 + gb0);                    \
      af[mi][1] = *(const bf16x8*)(Ab_ + mi * 2048 + gb1);                    \
    }                                                                         \
    _Pragma("unroll") for (int ni = 0; ni < 2; ++ni) {                        \
      bfrag[ni][0] = *(const bf16x8*)(Bb_ + ni * 2048 + gb0);                 \
      bfrag[ni][1] = *(const bf16x8*)(Bb_ + ni * 2048 + gb1);                 \
    }                                                                         \
  } while (0)

#define MFMAQ(QM_, QN_)                                                       \
  do {                                                                        \
    __builtin_amdgcn_s_barrier();                                             \
    asm volatile("s_waitcnt lgkmcnt(0)" ::: "memory");                        \
    __builtin_amdgcn_s_setprio(1);                                            \
    _Pragma("unroll") for (int mi = 0; mi < 4; ++mi) {                        \
      _Pragma("unroll") for (int ni = 0; ni < 2; ++ni) {                      \
        f32x4& a_ = acc[(QM_) * 4 + mi][(QN_) * 2 + ni];                      \
        a_ = MFMA_BF16(af[mi][0], bfrag[ni][0], a_);                          \
        a_ = MFMA_BF16(af[mi][1], bfrag[ni][1], a_);                          \
      }                                                                       \
    }                                                                         \
    __builtin_amdgcn_s_setprio(0);                                            \
    __builtin_amdgcn_s_barrier();                                             \
  } while (0)

#define STAGE_A8(B_, H_, KT_)                                                 \
  do {                                                                        \
    char* d_ = (char*)As8 + ((B_) * 2 + (H_)) * 16384 + wave * 1024;          \
    GLDS16(A + (size_t)(m0 + (H_) * 128 + srow) * 1024 + (KT_) * 64 + sgo,    \
           d_);                                                               \
    GLDS16(A + (size_t)(m0 + (H_) * 128 + 64 + srow) * 1024 + (KT_) * 64 +    \
               sgo,                                                           \
           d_ + 8192);                                                        \
  } while (0)

#define STAGE_B8(B_, H_, KT_)                                                 \
  do {                                                                        \
    char* d_ = (char*)Bs8 + ((B_) * 2 + (H_)) * 16384 + wave * 1024;          \
    GLDS16(W + (size_t)(n0 + (H_) * 128 + srow) * 1024 + (KT_) * 64 + sgo,    \
           d_);                                                               \
    GLDS16(W + (size_t)(n0 + (H_) * 128 + 64 + srow) * 1024 + (KT_) * 64 +    \
               sgo,                                                           \
           d_ + 8192);                                                        \
  } while (0)

__global__ __launch_bounds__(512, 2) void gemm_qkv8(
    const __bf16* __restrict__ Aq, const __bf16* __restrict__ Ak,
    const __bf16* __restrict__ Av, const __bf16* __restrict__ Wqb,
    const __bf16* __restrict__ Wkb, const __bf16* __restrict__ Wvb,
    const float* __restrict__ bq, const float* __restrict__ bk,
    const float* __restrict__ bv, __bf16* __restrict__ Qw,
    __bf16* __restrict__ Kw, __bf16* __restrict__ Vw) {
  __shared__ __align__(16) __bf16 As8[2][2][128 * 64];  // [buf][half][r*64+k]
  __shared__ __align__(16) __bf16 Bs8[2][2][128 * 64];

  // bijective XCD swizzle: 384 blocks, 48 per XCD
  int bid = (blockIdx.x & 7) * 48 + (blockIdx.x >> 3);
  const int seg = bid >> 7;
  bid &= 127;
  const int m0 = (bid & 31) * 256;
  const int n0 = (bid >> 5) * 256;

  const __bf16* __restrict__ A = seg == 0 ? Aq : seg == 1 ? Ak : Av;
  const __bf16* __restrict__ W = seg == 0 ? Wqb : seg == 1 ? Wkb : Wvb;
  const float* __restrict__ bias = seg == 0 ? bq : seg == 1 ? bk : bv;
  __bf16* __restrict__ out = seg == 0 ? Qw : seg == 1 ? Kw : Vw;
  const int mode = (seg == 2) ? 2 : 1;

  const int tid = threadIdx.x;
  const int wave = tid >> 6, lane = tid & 63;
  const int col = lane & 15, quad = lane >> 4;
  const int wm = wave >> 2, wn = wave & 3;

  // staging geometry: slot s = i*512+tid; row=s>>3, LDS granule gs=s&7 holds
  // global granule gs^(row&7); i=1 is row+64, same XOR (64%8==0)
  const int srow = tid >> 3;
  const int sgo = ((tid & 7) ^ (srow & 7)) * 8;
  // frag-read granule byte offsets (invert swizzle); row_h&7 == col&7
  const int gb0 = ((quad) ^ (col & 7)) * 16;
  const int gb1 = ((quad + 4) ^ (col & 7)) * 16;
  const int rowA = (wm * 64 + col) * 128;
  const int rowB = (wn * 32 + col) * 128;

  f32x4 acc[8][4] = {};
  bf16x8 af[4][2], bfrag[2][2];

  // prologue: tile0 fully + tile1 halves A0,B0 (12 loads); force tile0.
  STAGE_A8(0, 0, 0);
  STAGE_B8(0, 0, 0);
  STAGE_A8(0, 1, 0);
  STAGE_B8(0, 1, 0);
  STAGE_A8(1, 0, 1);
  STAGE_B8(1, 0, 1);
  asm volatile("s_waitcnt vmcnt(4)" ::: "memory");
  __builtin_amdgcn_s_barrier();

#pragma unroll 2
  for (int t = 0; t < 16; ++t) {
    const int buf = t & 1;
    // phase 0: quadrant (0,0)
    READQ(buf, 0, 0);
    if (t < 15)
      STAGE_A8(buf ^ 1, 1, t + 1);
    else
      asm volatile("s_waitcnt vmcnt(0)" ::: "memory");
    MFMAQ(0, 0);
    // phase 1: quadrant (0,1)
    READQ(buf, 0, 1);
    if (t < 15) STAGE_B8(buf ^ 1, 1, t + 1);
    MFMAQ(0, 1);
    // phase 2: quadrant (1,0)
    READQ(buf, 1, 0);
    if (t < 14) STAGE_A8(buf, 0, t + 2);
    MFMAQ(1, 0);
    // phase 3: quadrant (1,1)
    READQ(buf, 1, 1);
    if (t < 14) STAGE_B8(buf, 0, t + 2);
    asm volatile("s_waitcnt vmcnt(4)" ::: "memory");
    MFMAQ(1, 1);
  }

  // epilogue: C/D row = quad*4+r within each 16x16 fragment
#pragma unroll
  for (int an = 0; an < 4; ++an) {
    const int n = n0 + (an >> 1) * 128 + wn * 32 + (an & 1) * 16 + col;
    const float bb = bias[n];
    const int hh = n >> 6, dk = n & 63;
#pragma unroll
    for (int am = 0; am < 8; ++am) {
#pragma unroll
      for (int r = 0; r < 4; ++r) {
        const int m =
            m0 + (am >> 2) * 128 + wm * 64 + (am & 3) * 16 + quad * 4 + r;
        const int b_ = m >> 11, s_ = m & 2047;
        const size_t idx =
            (mode == 1) ? ((size_t)(b_ * 16 + hh) * 2048 + s_) * 64 + dk
                        : ((size_t)(b_ * 16 + hh) * 64 + dk) * 2048 + s_;
        out[idx] = (__bf16)(acc[am][an][r] + bb);
      }
    }
  }
}

#undef READQ
#undef MFMAQ
#undef STAGE_A8
#undef STAGE_B8

// ---------------------------------------------------------------------------
// Causal flash attention (unchanged — verified).
// ---------------------------------------------------------------------------
__global__ __launch_bounds__(256, 4) void flash_attn(
    const __bf16* __restrict__ Q, const __bf16* __restrict__ K,
    const __bf16* __restrict__ Vt, __bf16* __restrict__ ctx) {
  __shared__ __align__(16) __bf16 Ks[64 * 64];
  __shared__ __align__(16) __bf16 Vs[64 * 64];
  __shared__ __align__(16) __bf16 Pb[4][2][16 * 72];

  const int tid = threadIdx.x;
  const int wave = tid >> 6, lane = tid & 63;
  const int col = lane & 15, quad = lane >> 4;
  const int bh = blockIdx.x >> 4;
  const int pair = blockIdx.x & 15;
  const int b = bh >> 4, h = bh & 15;
  const int t_lo = pair, t_hi = 31 - pair;
  const int q0f[2] = {t_lo * 64 + wave * 16, t_hi * 64 + wave * 16};

  constexpr float SCL = 0.18033688011112042f;  // (1/8) * log2(e)

  bf16x8 qf[2][2];
#pragma unroll
  for (int f = 0; f < 2; ++f) {
    const __bf16* Qp = Q + ((size_t)bh * kS + q0f[f] + col) * 64 + quad * 8;
    qf[f][0] = *(const bf16x8*)Qp;
    qf[f][1] = *(const bf16x8*)(Qp + 32);
  }

  f32x4 o[2][4] = {};
  f32x4 lacc[2] = {};
  bf16x8 ones;
#pragma unroll
  for (int i = 0; i < 8; ++i) ones[i] = (__bf16)1.0f;

  const __bf16* Kg = K + (size_t)bh * kS * 64;
  const __bf16* Vg = Vt + (size_t)bh * 64 * kS;

  const int row0 = tid >> 3, g0 = (tid & 7) ^ (row0 & 7);
  const int row1 = (256 + tid) >> 3, g1 = (tid & 7) ^ (row1 & 7);
  char* KsB = (char*)Ks + wave * 1024;
  char* VsB = (char*)Vs + wave * 1024;

  const int fgoff0 = ((quad) ^ (col & 7)) * 16;
  const int fgoff1 = ((quad + 4) ^ (col & 7)) * 16;
  const int maskbase = wave * 16 + quad * 4;

  __bf16* Pw0 = &Pb[wave][0][0];
  __bf16* Pw1 = &Pb[wave][1][0];
  const __bf16* Pr0 = Pw0 + col * 72 + quad * 8;
  const __bf16* Pr1 = Pw1 + col * 72 + quad * 8;

  auto body = [&](int c, bool lo, bool d0, bool d1) {
    const int k0 = c * 64;
    GLDS16(Kg + (size_t)(k0 + row0) * 64 + g0 * 8, KsB);
    GLDS16(Vg + (size_t)row0 * kS + k0 + g0 * 8, VsB);
    GLDS16(Kg + (size_t)(k0 + row1) * 64 + g1 * 8, KsB + 4096);
    GLDS16(Vg + (size_t)row1 * kS + k0 + g1 * 8, VsB + 4096);
    __syncthreads();

    f32x4 s[2][4];
#pragma unroll
    for (int kt = 0; kt < 4; ++kt) {
      const char* kp = (const char*)Ks + (kt * 16 + col) * 128;
      const bf16x8 kf0 = *(const bf16x8*)(kp + fgoff0);
      const bf16x8 kf1 = *(const bf16x8*)(kp + fgoff1);
      f32x4 z = {};
      s[1][kt] = MFMA_BF16(qf[1][1], kf1, MFMA_BF16(qf[1][0], kf0, z));
      if (lo) s[0][kt] = MFMA_BF16(qf[0][1], kf1, MFMA_BF16(qf[0][0], kf0, z));
    }
#pragma unroll
    for (int kt = 0; kt < 4; ++kt) {
#pragma unroll
      for (int r = 0; r < 4; ++r) {
        float pv1 = __builtin_amdgcn_exp2f(s[1][kt][r] * SCL);
        if (d1 && (kt * 16 + col > maskbase + r)) pv1 = 0.0f;
        Pw1[(quad * 4 + r) * 72 + kt * 16 + col] = (__bf16)pv1;
        if (lo) {
          float pv0 = __builtin_amdgcn_exp2f(s[0][kt][r] * SCL);
          if (d0 && (kt * 16 + col > maskbase + r)) pv0 = 0.0f;
          Pw0[(quad * 4 + r) * 72 + kt * 16 + col] = (__bf16)pv0;
        }
      }
    }
    __threadfence_block();
    const bf16x8 pf1a = *(const bf16x8*)Pr1;
    const bf16x8 pf1b = *(const bf16x8*)(Pr1 + 32);
    bf16x8 pf0a = {}, pf0b = {};
    if (lo) {
      pf0a = *(const bf16x8*)Pr0;
      pf0b = *(const bf16x8*)(Pr0 + 32);
    }
#pragma unroll
    for (int dt = 0; dt < 4; ++dt) {
      const char* vp = (const char*)Vs + (dt * 16 + col) * 128;
      const bf16x8 vf0 = *(const bf16x8*)(vp + fgoff0);
      const bf16x8 vf1 = *(const bf16x8*)(vp + fgoff1);
      o[1][dt] = MFMA_BF16(pf1b, vf1, MFMA_BF16(pf1a, vf0, o[1][dt]));
      if (lo) o[0][dt] = MFMA_BF16(pf0b, vf1, MFMA_BF16(pf0a, vf0, o[0][dt]));
    }
    lacc[1] = MFMA_BF16(pf1b, ones, MFMA_BF16(pf1a, ones, lacc[1]));
    if (lo) lacc[0] = MFMA_BF16(pf0b, ones, MFMA_BF16(pf0a, ones, lacc[0]));
    __syncthreads();
  };

  for (int c = 0; c <= t_lo; ++c) body(c, true, c == t_lo, false);
  for (int c = t_lo + 1; c <= t_hi; ++c) body(c, false, false, c == t_hi);

#pragma unroll
  for (int f = 0; f < 2; ++f) {
#pragma unroll
    for (int r = 0; r < 4; ++r) {
      const float inv = 1.0f / lacc[f][r];
      const int srow = q0f[f] + quad * 4 + r;
      __bf16* cp = ctx + ((size_t)b * kS + srow) * kD + h * 64 + col;
#pragma unroll
      for (int dt = 0; dt < 4; ++dt)
        cp[dt * 16] = (__bf16)(o[f][dt][r] * inv);
    }
  }
}

// ---------------------------------------------------------------------------
extern "C" void kernel_launch(void* const* d_in, const int* in_sizes, int n_in,
                              void* d_out, int out_size, void* d_ws, size_t ws_size,
                              hipStream_t stream) {
  const float* query = (const float*)d_in[0];
  const float* key_  = (const float*)d_in[1];
  const float* value = (const float*)d_in[2];
  const float* Wq = (const float*)d_in[4];
  const float* bq = (const float*)d_in[5];
  const float* Wk = (const float*)d_in[6];
  const float* bk = (const float*)d_in[7];
  const float* Wv = (const float*)d_in[8];
  const float* bv = (const float*)d_in[9];
  const float* Wo = (const float*)d_in[10];
  const float* bo = (const float*)d_in[11];

  const size_t e = (size_t)kM * kD;       // 8,388,608
  const size_t w = (size_t)kD * kD;       // 1,048,576
  float* out = (float*)d_out;

  const size_t REQ = (6 * e + 4 * w) * sizeof(__bf16);  // ~109 MB

  if (ws_size >= REQ) {
    // fused path
    __bf16* Qw  = (__bf16*)d_ws;
    __bf16* Kw  = Qw + e;
    __bf16* Vw  = Kw + e;     // [B,H,64,S]
    __bf16* Aq  = Vw + e;     // reused as ctx after gemm_qkv8
    __bf16* Ak  = Aq + e;
    __bf16* Av  = Ak + e;
    __bf16* Wqb = Av + e;
    __bf16* Wkb = Wqb + w;
    __bf16* Wvb = Wkb + w;
    __bf16* Wob = Wvb + w;

    cvt_act3<<<3 * 4096, 256, 0, stream>>>(query, key_, value, Aq, Ak, Av);
    cvt_w4<<<4 * 512, 256, 0, stream>>>(Wq, Wk, Wv, Wo, Wqb, Wkb, Wvb, Wob);
    gemm_qkv8<<<384, 512, 0, stream>>>(Aq, Ak, Av, Wqb, Wkb, Wvb, bq, bk, bv,
                                       Qw, Kw, Vw);
    flash_attn<<<kB * kH * 16, 256, 0, stream>>>(Qw, Kw, Vw, Aq);  // ctx -> Aq
    gemm_one<0, float><<<512, 256, 0, stream>>>(Aq, Wob, bo, out);
  } else {
    // sequential fallback (round-3 layout, BK=64 gemm)
    __bf16* Qw = (__bf16*)d_ws;
    __bf16* Kw = Qw + e;
    __bf16* Vw = Kw + e;
    __bf16* Ab = Vw + e;
    __bf16* Wb = Ab + e;

    const int actg = (int)(e / 8 / 256);
    const int wg = (int)(w / 8 / 256);
    cvt_f32_bf16<<<actg, 256, 0, stream>>>(query, Ab, (int)(e / 8));
    cvt_f32_bf16<<<wg, 256, 0, stream>>>(Wq, Wb, (int)(w / 8));
    gemm_one<1, __bf16><<<512, 256, 0, stream>>>(Ab, Wb, bq, Qw);
    cvt_f32_bf16<<<actg, 256, 0, stream>>>(key_, Ab, (int)(e / 8));
    cvt_f32_bf16<<<wg, 256, 0, stream>>>(Wk, Wb, (int)(w / 8));
    gemm_one<1, __bf16><<<512, 256, 0, stream>>>(Ab, Wb, bk, Kw);
    cvt_f32_bf16<<<actg, 256, 0, stream>>>(value, Ab, (int)(e / 8));
    cvt_f32_bf16<<<wg, 256, 0, stream>>>(Wv, Wb, (int)(w / 8));
    gemm_one<2, __bf16><<<512, 256, 0, stream>>>(Ab, Wb, bv, Vw);
    flash_attn<<<kB * kH * 16, 256, 0, stream>>>(Qw, Kw, Vw, Ab);
    cvt_f32_bf16<<<wg, 256, 0, stream>>>(Wo, Wb, (int)(w / 8));
    gemm_one<0, float><<<512, 256, 0, stream>>>(Ab, Wb, bo, out);
  }
}

// Round 2
// 373.094 us; speedup vs baseline: 1.0817x; 1.0817x over previous
//
#include <hip/hip_runtime.h>
#include <hip/hip_bf16.h>
#include <cstdint>
#include <cstddef>

// B=4, S=2048, D=1024, H=16, DK=64. Device I/O dtype: FLOAT32.
// Internal compute: bf16 MFMA with f32 accumulation.
static constexpr int kB = 4, kS = 2048, kD = 1024, kH = 16, kDK = 64;
static constexpr int kM = kB * kS;

typedef __attribute__((ext_vector_type(8))) __bf16 bf16x8;
typedef __attribute__((ext_vector_type(4))) float f32x4;

#define MFMA_BF16(a, b, c) __builtin_amdgcn_mfma_f32_16x16x32_bf16((a), (b), (c), 0, 0, 0)

#define GLDS16(gp, lp)                                                        \
  __builtin_amdgcn_global_load_lds(                                           \
      (__attribute__((address_space(1))) void*)(gp),                          \
      (__attribute__((address_space(3))) void*)(lp), 16, 0, 0)

// ---------------------------------------------------------------------------
// f32 -> bf16 converters
// ---------------------------------------------------------------------------
__device__ __forceinline__ bf16x8 cvt8(const float* s, int i) {
  const float4 a = ((const float4*)s)[i * 2 + 0];
  const float4 b = ((const float4*)s)[i * 2 + 1];
  bf16x8 o;
  o[0] = (__bf16)a.x; o[1] = (__bf16)a.y; o[2] = (__bf16)a.z; o[3] = (__bf16)a.w;
  o[4] = (__bf16)b.x; o[5] = (__bf16)b.y; o[6] = (__bf16)b.z; o[7] = (__bf16)b.w;
  return o;
}

__global__ __launch_bounds__(256) void cvt_f32_bf16(
    const float* __restrict__ src, __bf16* __restrict__ dst, int n8) {
  const int i = blockIdx.x * 256 + threadIdx.x;
  if (i >= n8) return;
  ((bf16x8*)dst)[i] = cvt8(src, i);
}

// three activations in one launch: 4096 blocks per tensor
__global__ __launch_bounds__(256) void cvt_act3(
    const float* __restrict__ a, const float* __restrict__ b,
    const float* __restrict__ c, __bf16* __restrict__ da,
    __bf16* __restrict__ db, __bf16* __restrict__ dc) {
  const int seg = blockIdx.x >> 12;
  const int i = (blockIdx.x & 4095) * 256 + threadIdx.x;
  const float* s = seg == 0 ? a : seg == 1 ? b : c;
  __bf16* d = seg == 0 ? da : seg == 1 ? db : dc;
  ((bf16x8*)d)[i] = cvt8(s, i);
}

// four weights in one launch: 512 blocks per tensor
__global__ __launch_bounds__(256) void cvt_w4(
    const float* __restrict__ a, const float* __restrict__ b,
    const float* __restrict__ c, const float* __restrict__ d,
    __bf16* __restrict__ da, __bf16* __restrict__ db,
    __bf16* __restrict__ dc, __bf16* __restrict__ dd) {
  const int seg = blockIdx.x >> 9;
  const int i = (blockIdx.x & 511) * 256 + threadIdx.x;
  const float* s = seg == 0 ? a : seg == 1 ? b : seg == 2 ? c : d;
  __bf16* o = seg == 0 ? da : seg == 1 ? db : seg == 2 ? dc : dd;
  ((bf16x8*)o)[i] = cvt8(s, i);
}

// ---------------------------------------------------------------------------
// Legacy 128x128 GEMM core (kept for gemm_one / fallback path).
// ---------------------------------------------------------------------------
template <typename OutT>
__device__ __forceinline__ void gemm_core(
    const __bf16* __restrict__ A, const __bf16* __restrict__ W,
    const float* __restrict__ bias, OutT* __restrict__ out, int mode, int bid,
    __bf16* As, __bf16* Ws) {
  const int tid = threadIdx.x;
  const int wave = tid >> 6, lane = tid & 63;
  const int col = lane & 15, quad = lane >> 4;
  const int m0 = (bid & 63) * 128;
  const int n0 = (bid >> 6) * 128;
  const int wr = (wave & 1) * 64, wc = (wave >> 1) * 64;

  f32x4 acc[4][4] = {};

  int srow[4], sgo[4];
#pragma unroll
  for (int i = 0; i < 4; ++i) {
    const int s = i * 256 + tid;
    srow[i] = s >> 3;
    sgo[i] = (((s & 7) ^ ((s >> 3) & 7))) * 8;
  }
  const int g0 = ((quad) ^ (col & 7)) * 16;
  const int g1 = ((quad + 4) ^ (col & 7)) * 16;

  for (int k0 = 0; k0 < 1024; k0 += 64) {
#pragma unroll
    for (int i = 0; i < 4; ++i) {
      GLDS16(A + (size_t)(m0 + srow[i]) * 1024 + k0 + sgo[i],
             (char*)As + i * 4096 + wave * 1024);
      GLDS16(W + (size_t)(n0 + srow[i]) * 1024 + k0 + sgo[i],
             (char*)Ws + i * 4096 + wave * 1024);
    }
    __syncthreads();
#pragma unroll
    for (int h = 0; h < 2; ++h) {
      const int go = h ? g1 : g0;
      bf16x8 af[4], wf[4];
#pragma unroll
      for (int t = 0; t < 4; ++t) {
        af[t] = *(const bf16x8*)((const char*)As + (wr + t * 16 + col) * 128 + go);
        wf[t] = *(const bf16x8*)((const char*)Ws + (wc + t * 16 + col) * 128 + go);
      }
#pragma unroll
      for (int rt = 0; rt < 4; ++rt)
#pragma unroll
        for (int ct = 0; ct < 4; ++ct)
          acc[rt][ct] = MFMA_BF16(af[rt], wf[ct], acc[rt][ct]);
    }
    __syncthreads();
  }

#pragma unroll
  for (int ct = 0; ct < 4; ++ct) {
    const int n = n0 + wc + ct * 16 + col;
    const float bb = bias[n];
#pragma unroll
    for (int rt = 0; rt < 4; ++rt) {
#pragma unroll
      for (int r = 0; r < 4; ++r) {
        const int m = m0 + wr + rt * 16 + quad * 4 + r;
        const float v = acc[rt][ct][r] + bb;
        size_t idx;
        if (mode == 0) {
          idx = (size_t)m * 1024 + n;
        } else {
          const int b = m >> 11, s = m & 2047;
          const int h = n >> 6, dk = n & 63;
          if (mode == 1)
            idx = ((size_t)(b * 16 + h) * 2048 + s) * 64 + dk;
          else
            idx = ((size_t)(b * 16 + h) * 64 + dk) * 2048 + s;
        }
        out[idx] = (OutT)v;
      }
    }
  }
}

template <int MODE, typename OutT>
__global__ __launch_bounds__(256) void gemm_one(
    const __bf16* __restrict__ A, const __bf16* __restrict__ W,
    const float* __restrict__ bias, OutT* __restrict__ out) {
  __shared__ __align__(16) __bf16 As[128 * 64];
  __shared__ __align__(16) __bf16 Ws[128 * 64];
  gemm_core<OutT>(A, W, bias, out, MODE, blockIdx.x, As, Ws);
}

// ---------------------------------------------------------------------------
// QKV projections: 256x256 tile, BK=64, 8 waves, m201-faithful 8-phase
// schedule over 2 K-tiles per iteration.
//
// Wave (wm=wave>>2, wn=wave&3) owns rows {wm*64..+63} U {128+wm*64..+63} and
// cols {wn*32..+31} U {128+wn*32..+31}; quadrant (qm,qn) maps to staged
// half-tiles (A-half qm, B-half qn). Phase order per tile:
// (0,0),(0,1),(1,0),(1,1) -> A-frags read at phases 0,2 and REUSED at 1,3
// (32 ds_read_b128 per K-tile instead of 48).
//
// Iteration i covers tiles 2i (buf0) and 2i+1 (buf1); ONE half-tile staged
// per phase (2 GLDS16):
//   ph0: b1.A1<-2i+1   ph1: b1.B1<-2i+1   ph2: b0.A0<-2i+2  ph3: b0.B0<-2i+2
//   ph4: b0.A1<-2i+2   ph5: b0.B1<-2i+2   ph6: b1.A0<-2i+3  ph7: b1.B0<-2i+3
// vmcnt(4) ONLY at ph3/ph7, after the MFMA cluster and BEFORE the closing
// barrier: drains everything needed by the next 4 phases, leaves 2 half-tiles
// (4 loads) in flight; issue->wait lead is >=3 phases (> HBM latency).
// WAR: every stage lands in a half whose last reader finished a full barrier
// earlier. rule #18: sched_barrier(0) after lgkmcnt(0); compiler memfence
// after each closing barrier so ds_reads can't float across raw s_barrier.
// ---------------------------------------------------------------------------
#define READA(B_, QM_)                                                        \
  do {                                                                        \
    const char* Ab_ = (const char*)As8 + ((B_) * 2 + (QM_)) * 16384 + rowA;   \
    _Pragma("unroll") for (int mi = 0; mi < 4; ++mi) {                        \
      af[mi][0] = *(const bf16x8*)(Ab_ + mi * 2048 + gb0);                    \
      af[mi][1] = *(const bf16x8*)(Ab_ + mi * 2048 + gb1);                    \
    }                                                                         \
  } while (0)

#define READB(B_, QN_)                                                        \
  do {                                                                        \
    const char* Bb_ = (const char*)Bs8 + ((B_) * 2 + (QN_)) * 16384 + rowB;   \
    _Pragma("unroll") for (int ni = 0; ni < 2; ++ni) {                        \
      bfrag[ni][0] = *(const bf16x8*)(Bb_ + ni * 2048 + gb0);                 \
      bfrag[ni][1] = *(const bf16x8*)(Bb_ + ni * 2048 + gb1);                 \
    }                                                                         \
  } while (0)

#define STAGE_AH(B_, H_, KT_)                                                 \
  do {                                                                        \
    char* d_ = (char*)As8 + ((B_) * 2 + (H_)) * 16384 + wave * 1024;          \
    GLDS16(A + (size_t)(m0 + (H_) * 128 + srow) * 1024 + (KT_) * 64 + sgo,    \
           d_);                                                               \
    GLDS16(A + (size_t)(m0 + (H_) * 128 + 64 + srow) * 1024 + (KT_) * 64 +    \
               sgo,                                                           \
           d_ + 8192);                                                        \
  } while (0)

#define STAGE_BH(B_, H_, KT_)                                                 \
  do {                                                                        \
    char* d_ = (char*)Bs8 + ((B_) * 2 + (H_)) * 16384 + wave * 1024;          \
    GLDS16(W + (size_t)(n0 + (H_) * 128 + srow) * 1024 + (KT_) * 64 + sgo,    \
           d_);                                                               \
    GLDS16(W + (size_t)(n0 + (H_) * 128 + 64 + srow) * 1024 + (KT_) * 64 +    \
               sgo,                                                           \
           d_ + 8192);                                                        \
  } while (0)

#define MFMAQ_BODY(QM_, QN_)                                                  \
  __builtin_amdgcn_s_barrier();                                               \
  asm volatile("s_waitcnt lgkmcnt(0)" ::: "memory");                          \
  __builtin_amdgcn_sched_barrier(0);                                          \
  __builtin_amdgcn_s_setprio(1);                                              \
  _Pragma("unroll") for (int mi = 0; mi < 4; ++mi) {                          \
    _Pragma("unroll") for (int ni = 0; ni < 2; ++ni) {                        \
      f32x4& a_ = acc[(QM_) * 4 + mi][(QN_) * 2 + ni];                        \
      a_ = MFMA_BF16(af[mi][0], bfrag[ni][0], a_);                            \
      a_ = MFMA_BF16(af[mi][1], bfrag[ni][1], a_);                            \
    }                                                                         \
  }                                                                           \
  __builtin_amdgcn_s_setprio(0);

#define MFMAQ(QM_, QN_)                                                       \
  do {                                                                        \
    MFMAQ_BODY(QM_, QN_)                                                      \
    __builtin_amdgcn_s_barrier();                                             \
    asm volatile("" ::: "memory");                                            \
  } while (0)

#define MFMAQ_W(QM_, QN_, N_)                                                 \
  do {                                                                        \
    MFMAQ_BODY(QM_, QN_)                                                      \
    asm volatile("s_waitcnt vmcnt(" #N_ ")" ::: "memory");                    \
    __builtin_amdgcn_s_barrier();                                             \
    asm volatile("" ::: "memory");                                            \
  } while (0)

__global__ __launch_bounds__(512, 2) void gemm_qkv8(
    const __bf16* __restrict__ Aq, const __bf16* __restrict__ Ak,
    const __bf16* __restrict__ Av, const __bf16* __restrict__ Wqb,
    const __bf16* __restrict__ Wkb, const __bf16* __restrict__ Wvb,
    const float* __restrict__ bq, const float* __restrict__ bk,
    const float* __restrict__ bv, __bf16* __restrict__ Qw,
    __bf16* __restrict__ Kw, __bf16* __restrict__ Vw) {
  __shared__ __align__(16) __bf16 As8[2][2][128 * 64];  // [buf][half][r*64+k]
  __shared__ __align__(16) __bf16 Bs8[2][2][128 * 64];

  // plain block order (no XCD swizzle: working set is L3-resident)
  const int seg = blockIdx.x >> 7;
  const int bid = blockIdx.x & 127;
  const int m0 = (bid & 31) * 256;
  const int n0 = (bid >> 5) * 256;

  const __bf16* __restrict__ A = seg == 0 ? Aq : seg == 1 ? Ak : Av;
  const __bf16* __restrict__ W = seg == 0 ? Wqb : seg == 1 ? Wkb : Wvb;
  const float* __restrict__ bias = seg == 0 ? bq : seg == 1 ? bk : bv;
  __bf16* __restrict__ out = seg == 0 ? Qw : seg == 1 ? Kw : Vw;
  const int mode = (seg == 2) ? 2 : 1;

  const int tid = threadIdx.x;
  const int wave = tid >> 6, lane = tid & 63;
  const int col = lane & 15, quad = lane >> 4;
  const int wm = wave >> 2, wn = wave & 3;

  // staging geometry: row = tid>>3 (64 rows/GLDS across 512 threads), LDS
  // granule gs = tid&7 holds global granule gs^(row&7) (involution swizzle)
  const int srow = tid >> 3;
  const int sgo = ((tid & 7) ^ (srow & 7)) * 8;
  // frag-read granule byte offsets (invert swizzle); row&7 == col&7 for all
  // fragment rows (row = 16*mi + 64*wm + col etc.)
  const int gb0 = ((quad) ^ (col & 7)) * 16;
  const int gb1 = ((quad + 4) ^ (col & 7)) * 16;
  const int rowA = (wm * 64 + col) * 128;
  const int rowB = (wn * 32 + col) * 128;

  f32x4 acc[8][4] = {};
  bf16x8 af[4][2], bfrag[2][2];

  // prologue: tile0 all 4 halves + tile1 A0,B0 (12 loads); drain tile0.
  STAGE_AH(0, 0, 0);
  STAGE_BH(0, 0, 0);
  STAGE_AH(0, 1, 0);
  STAGE_BH(0, 1, 0);
  STAGE_AH(1, 0, 1);
  STAGE_BH(1, 0, 1);
  asm volatile("s_waitcnt vmcnt(4)" ::: "memory");
  __builtin_amdgcn_s_barrier();
  asm volatile("" ::: "memory");

  for (int i = 0; i < 7; ++i) {
    const int kt1 = 2 * i + 1, kt2 = 2 * i + 2, kt3 = 2 * i + 3;
    // tile 2i (buf0)
    READA(0, 0); READB(0, 0); STAGE_AH(1, 1, kt1); MFMAQ(0, 0);
    READB(0, 1);              STAGE_BH(1, 1, kt1); MFMAQ(0, 1);
    READA(0, 1); READB(0, 0); STAGE_AH(0, 0, kt2); MFMAQ(1, 0);
    READB(0, 1);              STAGE_BH(0, 0, kt2); MFMAQ_W(1, 1, 4);
    // tile 2i+1 (buf1)
    READA(1, 0); READB(1, 0); STAGE_AH(0, 1, kt2); MFMAQ(0, 0);
    READB(1, 1);              STAGE_BH(0, 1, kt2); MFMAQ(0, 1);
    READA(1, 1); READB(1, 0); STAGE_AH(1, 0, kt3); MFMAQ(1, 0);
    READB(1, 1);              STAGE_BH(1, 0, kt3); MFMAQ_W(1, 1, 4);
  }
  // tail iteration: tiles 14 (buf0), 15 (buf1); no stages past tile 15.
  READA(0, 0); READB(0, 0); STAGE_AH(1, 1, 15); MFMAQ(0, 0);
  READB(0, 1);              STAGE_BH(1, 1, 15); MFMAQ(0, 1);
  READA(0, 1); READB(0, 0);                     MFMAQ(1, 0);
  READB(0, 1);                                  MFMAQ_W(1, 1, 0);
  READA(1, 0); READB(1, 0);                     MFMAQ(0, 0);
  READB(1, 1);                                  MFMAQ(0, 1);
  READA(1, 1); READB(1, 0);                     MFMAQ(1, 0);
  READB(1, 1);                                  MFMAQ(1, 1);

  // epilogue: C/D row = quad*4+r within each 16x16 fragment
#pragma unroll
  for (int an = 0; an < 4; ++an) {
    const int n = n0 + (an >> 1) * 128 + wn * 32 + (an & 1) * 16 + col;
    const float bb = bias[n];
    const int hh = n >> 6, dk = n & 63;
#pragma unroll
    for (int am = 0; am < 8; ++am) {
#pragma unroll
      for (int r = 0; r < 4; ++r) {
        const int m =
            m0 + (am >> 2) * 128 + wm * 64 + (am & 3) * 16 + quad * 4 + r;
        const int b_ = m >> 11, s_ = m & 2047;
        const size_t idx =
            (mode == 1) ? ((size_t)(b_ * 16 + hh) * 2048 + s_) * 64 + dk
                        : ((size_t)(b_ * 16 + hh) * 64 + dk) * 2048 + s_;
        out[idx] = (__bf16)(acc[am][an][r] + bb);
      }
    }
  }
}

#undef READA
#undef READB
#undef STAGE_AH
#undef STAGE_BH
#undef MFMAQ_BODY
#undef MFMAQ
#undef MFMAQ_W

// ---------------------------------------------------------------------------
// Causal flash attention (unchanged — verified).
// ---------------------------------------------------------------------------
__global__ __launch_bounds__(256, 4) void flash_attn(
    const __bf16* __restrict__ Q, const __bf16* __restrict__ K,
    const __bf16* __restrict__ Vt, __bf16* __restrict__ ctx) {
  __shared__ __align__(16) __bf16 Ks[64 * 64];
  __shared__ __align__(16) __bf16 Vs[64 * 64];
  __shared__ __align__(16) __bf16 Pb[4][2][16 * 72];

  const int tid = threadIdx.x;
  const int wave = tid >> 6, lane = tid & 63;
  const int col = lane & 15, quad = lane >> 4;
  const int bh = blockIdx.x >> 4;
  const int pair = blockIdx.x & 15;
  const int b = bh >> 4, h = bh & 15;
  const int t_lo = pair, t_hi = 31 - pair;
  const int q0f[2] = {t_lo * 64 + wave * 16, t_hi * 64 + wave * 16};

  constexpr float SCL = 0.18033688011112042f;  // (1/8) * log2(e)

  bf16x8 qf[2][2];
#pragma unroll
  for (int f = 0; f < 2; ++f) {
    const __bf16* Qp = Q + ((size_t)bh * kS + q0f[f] + col) * 64 + quad * 8;
    qf[f][0] = *(const bf16x8*)Qp;
    qf[f][1] = *(const bf16x8*)(Qp + 32);
  }

  f32x4 o[2][4] = {};
  f32x4 lacc[2] = {};
  bf16x8 ones;
#pragma unroll
  for (int i = 0; i < 8; ++i) ones[i] = (__bf16)1.0f;

  const __bf16* Kg = K + (size_t)bh * kS * 64;
  const __bf16* Vg = Vt + (size_t)bh * 64 * kS;

  const int row0 = tid >> 3, g0 = (tid & 7) ^ (row0 & 7);
  const int row1 = (256 + tid) >> 3, g1 = (tid & 7) ^ (row1 & 7);
  char* KsB = (char*)Ks + wave * 1024;
  char* VsB = (char*)Vs + wave * 1024;

  const int fgoff0 = ((quad) ^ (col & 7)) * 16;
  const int fgoff1 = ((quad + 4) ^ (col & 7)) * 16;
  const int maskbase = wave * 16 + quad * 4;

  __bf16* Pw0 = &Pb[wave][0][0];
  __bf16* Pw1 = &Pb[wave][1][0];
  const __bf16* Pr0 = Pw0 + col * 72 + quad * 8;
  const __bf16* Pr1 = Pw1 + col * 72 + quad * 8;

  auto body = [&](int c, bool lo, bool d0, bool d1) {
    const int k0 = c * 64;
    GLDS16(Kg + (size_t)(k0 + row0) * 64 + g0 * 8, KsB);
    GLDS16(Vg + (size_t)row0 * kS + k0 + g0 * 8, VsB);
    GLDS16(Kg + (size_t)(k0 + row1) * 64 + g1 * 8, KsB + 4096);
    GLDS16(Vg + (size_t)row1 * kS + k0 + g1 * 8, VsB + 4096);
    __syncthreads();

    f32x4 s[2][4];
#pragma unroll
    for (int kt = 0; kt < 4; ++kt) {
      const char* kp = (const char*)Ks + (kt * 16 + col) * 128;
      const bf16x8 kf0 = *(const bf16x8*)(kp + fgoff0);
      const bf16x8 kf1 = *(const bf16x8*)(kp + fgoff1);
      f32x4 z = {};
      s[1][kt] = MFMA_BF16(qf[1][1], kf1, MFMA_BF16(qf[1][0], kf0, z));
      if (lo) s[0][kt] = MFMA_BF16(qf[0][1], kf1, MFMA_BF16(qf[0][0], kf0, z));
    }
#pragma unroll
    for (int kt = 0; kt < 4; ++kt) {
#pragma unroll
      for (int r = 0; r < 4; ++r) {
        float pv1 = __builtin_amdgcn_exp2f(s[1][kt][r] * SCL);
        if (d1 && (kt * 16 + col > maskbase + r)) pv1 = 0.0f;
        Pw1[(quad * 4 + r) * 72 + kt * 16 + col] = (__bf16)pv1;
        if (lo) {
          float pv0 = __builtin_amdgcn_exp2f(s[0][kt][r] * SCL);
          if (d0 && (kt * 16 + col > maskbase + r)) pv0 = 0.0f;
          Pw0[(quad * 4 + r) * 72 + kt * 16 + col] = (__bf16)pv0;
        }
      }
    }
    __threadfence_block();
    const bf16x8 pf1a = *(const bf16x8*)Pr1;
    const bf16x8 pf1b = *(const bf16x8*)(Pr1 + 32);
    bf16x8 pf0a = {}, pf0b = {};
    if (lo) {
      pf0a = *(const bf16x8*)Pr0;
      pf0b = *(const bf16x8*)(Pr0 + 32);
    }
#pragma unroll
    for (int dt = 0; dt < 4; ++dt) {
      const char* vp = (const char*)Vs + (dt * 16 + col) * 128;
      const bf16x8 vf0 = *(const bf16x8*)(vp + fgoff0);
      const bf16x8 vf1 = *(const bf16x8*)(vp + fgoff1);
      o[1][dt] = MFMA_BF16(pf1b, vf1, MFMA_BF16(pf1a, vf0, o[1][dt]));
      if (lo) o[0][dt] = MFMA_BF16(pf0b, vf1, MFMA_BF16(pf0a, vf0, o[0][dt]));
    }
    lacc[1] = MFMA_BF16(pf1b, ones, MFMA_BF16(pf1a, ones, lacc[1]));
    if (lo) lacc[0] = MFMA_BF16(pf0b, ones, MFMA_BF16(pf0a, ones, lacc[0]));
    __syncthreads();
  };

  for (int c = 0; c <= t_lo; ++c) body(c, true, c == t_lo, false);
  for (int c = t_lo + 1; c <= t_hi; ++c) body(c, false, false, c == t_hi);

#pragma unroll
  for (int f = 0; f < 2; ++f) {
#pragma unroll
    for (int r = 0; r < 4; ++r) {
      const float inv = 1.0f / lacc[f][r];
      const int srow = q0f[f] + quad * 4 + r;
      __bf16* cp = ctx + ((size_t)b * kS + srow) * kD + h * 64 + col;
#pragma unroll
      for (int dt = 0; dt < 4; ++dt)
        cp[dt * 16] = (__bf16)(o[f][dt][r] * inv);
    }
  }
}

// ---------------------------------------------------------------------------
extern "C" void kernel_launch(void* const* d_in, const int* in_sizes, int n_in,
                              void* d_out, int out_size, void* d_ws, size_t ws_size,
                              hipStream_t stream) {
  const float* query = (const float*)d_in[0];
  const float* key_  = (const float*)d_in[1];
  const float* value = (const float*)d_in[2];
  const float* Wq = (const float*)d_in[4];
  const float* bq = (const float*)d_in[5];
  const float* Wk = (const float*)d_in[6];
  const float* bk = (const float*)d_in[7];
  const float* Wv = (const float*)d_in[8];
  const float* bv = (const float*)d_in[9];
  const float* Wo = (const float*)d_in[10];
  const float* bo = (const float*)d_in[11];

  const size_t e = (size_t)kM * kD;       // 8,388,608
  const size_t w = (size_t)kD * kD;       // 1,048,576
  float* out = (float*)d_out;

  const size_t REQ = (6 * e + 4 * w) * sizeof(__bf16);  // ~109 MB

  if (ws_size >= REQ) {
    // fused path
    __bf16* Qw  = (__bf16*)d_ws;
    __bf16* Kw  = Qw + e;
    __bf16* Vw  = Kw + e;     // [B,H,64,S]
    __bf16* Aq  = Vw + e;     // reused as ctx after gemm_qkv8
    __bf16* Ak  = Aq + e;
    __bf16* Av  = Ak + e;
    __bf16* Wqb = Av + e;
    __bf16* Wkb = Wqb + w;
    __bf16* Wvb = Wkb + w;
    __bf16* Wob = Wvb + w;

    cvt_act3<<<3 * 4096, 256, 0, stream>>>(query, key_, value, Aq, Ak, Av);
    cvt_w4<<<4 * 512, 256, 0, stream>>>(Wq, Wk, Wv, Wo, Wqb, Wkb, Wvb, Wob);
    gemm_qkv8<<<384, 512, 0, stream>>>(Aq, Ak, Av, Wqb, Wkb, Wvb, bq, bk, bv,
                                       Qw, Kw, Vw);
    flash_attn<<<kB * kH * 16, 256, 0, stream>>>(Qw, Kw, Vw, Aq);  // ctx -> Aq
    gemm_one<0, float><<<512, 256, 0, stream>>>(Aq, Wob, bo, out);
  } else {
    // sequential fallback (round-3 layout, BK=64 gemm)
    __bf16* Qw = (__bf16*)d_ws;
    __bf16* Kw = Qw + e;
    __bf16* Vw = Kw + e;
    __bf16* Ab = Vw + e;
    __bf16* Wb = Ab + e;

    const int actg = (int)(e / 8 / 256);
    const int wg = (int)(w / 8 / 256);
    cvt_f32_bf16<<<actg, 256, 0, stream>>>(query, Ab, (int)(e / 8));
    cvt_f32_bf16<<<wg, 256, 0, stream>>>(Wq, Wb, (int)(w / 8));
    gemm_one<1, __bf16><<<512, 256, 0, stream>>>(Ab, Wb, bq, Qw);
    cvt_f32_bf16<<<actg, 256, 0, stream>>>(key_, Ab, (int)(e / 8));
    cvt_f32_bf16<<<wg, 256, 0, stream>>>(Wk, Wb, (int)(w / 8));
    gemm_one<1, __bf16><<<512, 256, 0, stream>>>(Ab, Wb, bk, Kw);
    cvt_f32_bf16<<<actg, 256, 0, stream>>>(value, Ab, (int)(e / 8));
    cvt_f32_bf16<<<wg, 256, 0, stream>>>(Wv, Wb, (int)(w / 8));
    gemm_one<2, __bf16><<<512, 256, 0, stream>>>(Ab, Wb, bv, Vw);
    flash_attn<<<kB * kH * 16, 256, 0, stream>>>(Qw, Kw, Vw, Ab);
    cvt_f32_bf16<<<wg, 256, 0, stream>>>(Wo, Wb, (int)(w / 8));
    gemm_one<0, float><<<512, 256, 0, stream>>>(Ab, Wb, bo, out);
  }
}

// Round 4
// 364.824 us; speedup vs baseline: 1.1062x; 1.0227x over previous
//
#include <hip/hip_runtime.h>
#include <hip/hip_bf16.h>
#include <cstdint>
#include <cstddef>

// B=4, S=2048, D=1024, H=16, DK=64. Device I/O dtype: FLOAT32.
// Internal compute: bf16 MFMA with f32 accumulation.
static constexpr int kB = 4, kS = 2048, kD = 1024, kH = 16, kDK = 64;
static constexpr int kM = kB * kS;

typedef __attribute__((ext_vector_type(8))) __bf16 bf16x8;
typedef __attribute__((ext_vector_type(4))) float f32x4;

#define MFMA_BF16(a, b, c) __builtin_amdgcn_mfma_f32_16x16x32_bf16((a), (b), (c), 0, 0, 0)

#define GLDS16(gp, lp)                                                        \
  __builtin_amdgcn_global_load_lds(                                           \
      (__attribute__((address_space(1))) void*)(gp),                          \
      (__attribute__((address_space(3))) void*)(lp), 16, 0, 0)

// ---------------------------------------------------------------------------
// f32 -> bf16 converters
// ---------------------------------------------------------------------------
__device__ __forceinline__ bf16x8 cvt8(const float* s, int i) {
  const float4 a = ((const float4*)s)[i * 2 + 0];
  const float4 b = ((const float4*)s)[i * 2 + 1];
  bf16x8 o;
  o[0] = (__bf16)a.x; o[1] = (__bf16)a.y; o[2] = (__bf16)a.z; o[3] = (__bf16)a.w;
  o[4] = (__bf16)b.x; o[5] = (__bf16)b.y; o[6] = (__bf16)b.z; o[7] = (__bf16)b.w;
  return o;
}

__global__ __launch_bounds__(256) void cvt_f32_bf16(
    const float* __restrict__ src, __bf16* __restrict__ dst, int n8) {
  const int i = blockIdx.x * 256 + threadIdx.x;
  if (i >= n8) return;
  ((bf16x8*)dst)[i] = cvt8(src, i);
}

// all 7 input tensors in ONE launch: 3x4096 activation blocks + 4x512 weight
__global__ __launch_bounds__(256) void cvt_all(
    const float* __restrict__ q, const float* __restrict__ k,
    const float* __restrict__ v, const float* __restrict__ wq,
    const float* __restrict__ wk, const float* __restrict__ wv,
    const float* __restrict__ wo, __bf16* __restrict__ dq,
    __bf16* __restrict__ dk, __bf16* __restrict__ dv,
    __bf16* __restrict__ dwq, __bf16* __restrict__ dwk,
    __bf16* __restrict__ dwv, __bf16* __restrict__ dwo) {
  int bi = blockIdx.x;
  if (bi < 3 * 4096) {
    const int seg = bi >> 12;
    const int i = (bi & 4095) * 256 + threadIdx.x;
    const float* s = seg == 0 ? q : seg == 1 ? k : v;
    __bf16* d = seg == 0 ? dq : seg == 1 ? dk : dv;
    ((bf16x8*)d)[i] = cvt8(s, i);
  } else {
    bi -= 3 * 4096;
    const int seg = bi >> 9;
    const int i = (bi & 511) * 256 + threadIdx.x;
    const float* s = seg == 0 ? wq : seg == 1 ? wk : seg == 2 ? wv : wo;
    __bf16* d = seg == 0 ? dwq : seg == 1 ? dwk : seg == 2 ? dwv : dwo;
    ((bf16x8*)d)[i] = cvt8(s, i);
  }
}

// ---------------------------------------------------------------------------
// GEMM core: C[M,N] = A[M,K]*W[N,K]^T + bias; 128x128 tile, BK=64
// (proven round-0 structure: 2-barrier K-loop, XOR-granule LDS swizzle,
//  0 bank conflicts, 86 us / MfmaUtil 24.7 on the QKV launch).
// mode 0: out[m*1024+n] ; mode 1: [b][h][s][dk] ; mode 2: [b][h][dk][s]
// ---------------------------------------------------------------------------
template <typename OutT>
__device__ __forceinline__ void gemm_core(
    const __bf16* __restrict__ A, const __bf16* __restrict__ W,
    const float* __restrict__ bias, OutT* __restrict__ out, int mode, int bid,
    __bf16* As, __bf16* Ws) {
  const int tid = threadIdx.x;
  const int wave = tid >> 6, lane = tid & 63;
  const int col = lane & 15, quad = lane >> 4;
  const int m0 = (bid & 63) * 128;
  const int n0 = (bid >> 6) * 128;
  const int wr = (wave & 1) * 64, wc = (wave >> 1) * 64;

  f32x4 acc[4][4] = {};

  int srow[4], sgo[4];
#pragma unroll
  for (int i = 0; i < 4; ++i) {
    const int s = i * 256 + tid;
    srow[i] = s >> 3;
    sgo[i] = (((s & 7) ^ ((s >> 3) & 7))) * 8;
  }
  const int g0 = ((quad) ^ (col & 7)) * 16;
  const int g1 = ((quad + 4) ^ (col & 7)) * 16;

  for (int k0 = 0; k0 < 1024; k0 += 64) {
#pragma unroll
    for (int i = 0; i < 4; ++i) {
      GLDS16(A + (size_t)(m0 + srow[i]) * 1024 + k0 + sgo[i],
             (char*)As + i * 4096 + wave * 1024);
      GLDS16(W + (size_t)(n0 + srow[i]) * 1024 + k0 + sgo[i],
             (char*)Ws + i * 4096 + wave * 1024);
    }
    __syncthreads();
#pragma unroll
    for (int h = 0; h < 2; ++h) {
      const int go = h ? g1 : g0;
      bf16x8 af[4], wf[4];
#pragma unroll
      for (int t = 0; t < 4; ++t) {
        af[t] = *(const bf16x8*)((const char*)As + (wr + t * 16 + col) * 128 + go);
        wf[t] = *(const bf16x8*)((const char*)Ws + (wc + t * 16 + col) * 128 + go);
      }
#pragma unroll
      for (int rt = 0; rt < 4; ++rt)
#pragma unroll
        for (int ct = 0; ct < 4; ++ct)
          acc[rt][ct] = MFMA_BF16(af[rt], wf[ct], acc[rt][ct]);
    }
    __syncthreads();
  }

#pragma unroll
  for (int ct = 0; ct < 4; ++ct) {
    const int n = n0 + wc + ct * 16 + col;
    const float bb = bias[n];
#pragma unroll
    for (int rt = 0; rt < 4; ++rt) {
#pragma unroll
      for (int r = 0; r < 4; ++r) {
        const int m = m0 + wr + rt * 16 + quad * 4 + r;
        const float v = acc[rt][ct][r] + bb;
        size_t idx;
        if (mode == 0) {
          idx = (size_t)m * 1024 + n;
        } else {
          const int b = m >> 11, s = m & 2047;
          const int h = n >> 6, dk = n & 63;
          if (mode == 1)
            idx = ((size_t)(b * 16 + h) * 2048 + s) * 64 + dk;
          else
            idx = ((size_t)(b * 16 + h) * 64 + dk) * 2048 + s;
        }
        out[idx] = (OutT)v;
      }
    }
  }
}

template <int MODE, typename OutT>
__global__ __launch_bounds__(256) void gemm_one(
    const __bf16* __restrict__ A, const __bf16* __restrict__ W,
    const float* __restrict__ bias, OutT* __restrict__ out) {
  __shared__ __align__(16) __bf16 As[128 * 64];
  __shared__ __align__(16) __bf16 Ws[128 * 64];
  gemm_core<OutT>(A, W, bias, out, MODE, blockIdx.x, As, Ws);
}

// Q/K/V projections fused into one 1536-block launch (round-0 proven)
__global__ __launch_bounds__(256) void gemm_qkv(
    const __bf16* __restrict__ Aq, const __bf16* __restrict__ Ak,
    const __bf16* __restrict__ Av, const __bf16* __restrict__ Wqb,
    const __bf16* __restrict__ Wkb, const __bf16* __restrict__ Wvb,
    const float* __restrict__ bq, const float* __restrict__ bk,
    const float* __restrict__ bv, __bf16* __restrict__ Qw,
    __bf16* __restrict__ Kw, __bf16* __restrict__ Vw) {
  __shared__ __align__(16) __bf16 As[128 * 64];
  __shared__ __align__(16) __bf16 Ws[128 * 64];
  const int seg = blockIdx.x >> 9;
  const int bid = blockIdx.x & 511;
  const __bf16* A = seg == 0 ? Aq : seg == 1 ? Ak : Av;
  const __bf16* W = seg == 0 ? Wqb : seg == 1 ? Wkb : Wvb;
  const float* bias = seg == 0 ? bq : seg == 1 ? bk : bv;
  __bf16* out = seg == 0 ? Qw : seg == 1 ? Kw : Vw;
  gemm_core<__bf16>(A, W, bias, out, seg == 2 ? 2 : 1, bid, As, Ws);
}

// ---------------------------------------------------------------------------
// Causal flash attention.
// K/V double-buffered with counted vmcnt (T3/T4 at body granularity). The
// old structure drained vmcnt(0) via __syncthreads on loads issued in the
// SAME body (zero lead, ~900 cyc exposed per iter). New: issue KV(c+1) at
// body top -> vmcnt(4) waits only KV(c), issued one full body (~5K cyc)
// earlier -> staging latency hidden. Raw s_barrier + memory clobbers replace
// the draining __syncthreads.
// WAR: KV(c+1) targets buf[(c+1)&1], last read in body c-1, whose reads
// completed (consumed by MFMA) before the trailing barrier we just passed.
// LDS 51200 B -> 3 blocks/CU (was 4); accepted for the latency win.
// ---------------------------------------------------------------------------
__global__ __launch_bounds__(256, 3) void flash_attn(
    const __bf16* __restrict__ Q, const __bf16* __restrict__ K,
    const __bf16* __restrict__ Vt, __bf16* __restrict__ ctx) {
  __shared__ __align__(16) __bf16 Ks[2][64 * 64];
  __shared__ __align__(16) __bf16 Vs[2][64 * 64];
  __shared__ __align__(16) __bf16 Pb[4][2][16 * 72];

  const int tid = threadIdx.x;
  const int wave = tid >> 6, lane = tid & 63;
  const int col = lane & 15, quad = lane >> 4;
  const int bh = blockIdx.x >> 4;
  const int pair = blockIdx.x & 15;
  const int b = bh >> 4, h = bh & 15;
  const int t_lo = pair, t_hi = 31 - pair;
  const int q0f[2] = {t_lo * 64 + wave * 16, t_hi * 64 + wave * 16};

  constexpr float SCL = 0.18033688011112042f;  // (1/8) * log2(e)

  bf16x8 qf[2][2];
#pragma unroll
  for (int f = 0; f < 2; ++f) {
    const __bf16* Qp = Q + ((size_t)bh * kS + q0f[f] + col) * 64 + quad * 8;
    qf[f][0] = *(const bf16x8*)Qp;
    qf[f][1] = *(const bf16x8*)(Qp + 32);
  }

  f32x4 o[2][4] = {};
  f32x4 lacc[2] = {};
  bf16x8 ones;
#pragma unroll
  for (int i = 0; i < 8; ++i) ones[i] = (__bf16)1.0f;

  const __bf16* Kg = K + (size_t)bh * kS * 64;
  const __bf16* Vg = Vt + (size_t)bh * 64 * kS;

  const int row0 = tid >> 3, g0 = (tid & 7) ^ (row0 & 7);
  const int row1 = (256 + tid) >> 3, g1 = (tid & 7) ^ (row1 & 7);

  const int fgoff0 = ((quad) ^ (col & 7)) * 16;
  const int fgoff1 = ((quad + 4) ^ (col & 7)) * 16;
  const int maskbase = wave * 16 + quad * 4;

  __bf16* Pw0 = &Pb[wave][0][0];
  __bf16* Pw1 = &Pb[wave][1][0];
  const __bf16* Pr0 = Pw0 + col * 72 + quad * 8;
  const __bf16* Pr1 = Pw1 + col * 72 + quad * 8;

  auto stage = [&](int c, int buf) {
    const int k0 = c * 64;
    char* KsB = (char*)Ks + buf * 8192 + wave * 1024;
    char* VsB = (char*)Vs + buf * 8192 + wave * 1024;
    GLDS16(Kg + (size_t)(k0 + row0) * 64 + g0 * 8, KsB);
    GLDS16(Vg + (size_t)row0 * kS + k0 + g0 * 8, VsB);
    GLDS16(Kg + (size_t)(k0 + row1) * 64 + g1 * 8, KsB + 4096);
    GLDS16(Vg + (size_t)row1 * kS + k0 + g1 * 8, VsB + 4096);
  };

  auto body = [&](int c, bool lo, bool d0, bool d1, bool stage_next) {
    // entry: trailing barrier of body(c-1) already passed.
    if (stage_next) {
      stage(c + 1, (c + 1) & 1);
      asm volatile("s_waitcnt vmcnt(4)" ::: "memory");  // KV(c) landed
    } else {
      asm volatile("s_waitcnt vmcnt(0)" ::: "memory");  // tail: drain all
    }
    __builtin_amdgcn_s_barrier();
    asm volatile("" ::: "memory");

    const char* Ksb = (const char*)Ks + (c & 1) * 8192;
    const char* Vsb = (const char*)Vs + (c & 1) * 8192;

    f32x4 s[2][4];
#pragma unroll
    for (int kt = 0; kt < 4; ++kt) {
      const char* kp = Ksb + (kt * 16 + col) * 128;
      const bf16x8 kf0 = *(const bf16x8*)(kp + fgoff0);
      const bf16x8 kf1 = *(const bf16x8*)(kp + fgoff1);
      f32x4 z = {};
      s[1][kt] = MFMA_BF16(qf[1][1], kf1, MFMA_BF16(qf[1][0], kf0, z));
      if (lo) s[0][kt] = MFMA_BF16(qf[0][1], kf1, MFMA_BF16(qf[0][0], kf0, z));
    }
#pragma unroll
    for (int kt = 0; kt < 4; ++kt) {
#pragma unroll
      for (int r = 0; r < 4; ++r) {
        float pv1 = __builtin_amdgcn_exp2f(s[1][kt][r] * SCL);
        if (d1 && (kt * 16 + col > maskbase + r)) pv1 = 0.0f;
        Pw1[(quad * 4 + r) * 72 + kt * 16 + col] = (__bf16)pv1;
        if (lo) {
          float pv0 = __builtin_amdgcn_exp2f(s[0][kt][r] * SCL);
          if (d0 && (kt * 16 + col > maskbase + r)) pv0 = 0.0f;
          Pw0[(quad * 4 + r) * 72 + kt * 16 + col] = (__bf16)pv0;
        }
      }
    }
    __threadfence_block();
    const bf16x8 pf1a = *(const bf16x8*)Pr1;
    const bf16x8 pf1b = *(const bf16x8*)(Pr1 + 32);
    bf16x8 pf0a = {}, pf0b = {};
    if (lo) {
      pf0a = *(const bf16x8*)Pr0;
      pf0b = *(const bf16x8*)(Pr0 + 32);
    }
#pragma unroll
    for (int dt = 0; dt < 4; ++dt) {
      const char* vp = Vsb + (dt * 16 + col) * 128;
      const bf16x8 vf0 = *(const bf16x8*)(vp + fgoff0);
      const bf16x8 vf1 = *(const bf16x8*)(vp + fgoff1);
      o[1][dt] = MFMA_BF16(pf1b, vf1, MFMA_BF16(pf1a, vf0, o[1][dt]));
      if (lo) o[0][dt] = MFMA_BF16(pf0b, vf1, MFMA_BF16(pf0a, vf0, o[0][dt]));
    }
    lacc[1] = MFMA_BF16(pf1b, ones, MFMA_BF16(pf1a, ones, lacc[1]));
    if (lo) lacc[0] = MFMA_BF16(pf0b, ones, MFMA_BF16(pf0a, ones, lacc[0]));

    __builtin_amdgcn_s_barrier();  // all waves done reading buf[c]
    asm volatile("" ::: "memory");
  };

  stage(0, 0);
  for (int c = 0; c <= t_lo; ++c) body(c, true, c == t_lo, false, c < t_hi);
  for (int c = t_lo + 1; c <= t_hi; ++c)
    body(c, false, false, c == t_hi, c < t_hi);

#pragma unroll
  for (int f = 0; f < 2; ++f) {
#pragma unroll
    for (int r = 0; r < 4; ++r) {
      const float inv = 1.0f / lacc[f][r];
      const int srow = q0f[f] + quad * 4 + r;
      __bf16* cp = ctx + ((size_t)b * kS + srow) * kD + h * 64 + col;
#pragma unroll
      for (int dt = 0; dt < 4; ++dt)
        cp[dt * 16] = (__bf16)(o[f][dt][r] * inv);
    }
  }
}

// ---------------------------------------------------------------------------
extern "C" void kernel_launch(void* const* d_in, const int* in_sizes, int n_in,
                              void* d_out, int out_size, void* d_ws, size_t ws_size,
                              hipStream_t stream) {
  const float* query = (const float*)d_in[0];
  const float* key_  = (const float*)d_in[1];
  const float* value = (const float*)d_in[2];
  const float* Wq = (const float*)d_in[4];
  const float* bq = (const float*)d_in[5];
  const float* Wk = (const float*)d_in[6];
  const float* bk = (const float*)d_in[7];
  const float* Wv = (const float*)d_in[8];
  const float* bv = (const float*)d_in[9];
  const float* Wo = (const float*)d_in[10];
  const float* bo = (const float*)d_in[11];

  const size_t e = (size_t)kM * kD;       // 8,388,608
  const size_t w = (size_t)kD * kD;       // 1,048,576
  float* out = (float*)d_out;

  const size_t REQ = (6 * e + 4 * w) * sizeof(__bf16);  // ~109 MB

  if (ws_size >= REQ) {
    // fused path
    __bf16* Qw  = (__bf16*)d_ws;
    __bf16* Kw  = Qw + e;
    __bf16* Vw  = Kw + e;     // [B,H,64,S]
    __bf16* Aq  = Vw + e;     // reused as ctx after gemm_qkv
    __bf16* Ak  = Aq + e;
    __bf16* Av  = Ak + e;
    __bf16* Wqb = Av + e;
    __bf16* Wkb = Wqb + w;
    __bf16* Wvb = Wkb + w;
    __bf16* Wob = Wvb + w;

    cvt_all<<<3 * 4096 + 4 * 512, 256, 0, stream>>>(
        query, key_, value, Wq, Wk, Wv, Wo, Aq, Ak, Av, Wqb, Wkb, Wvb, Wob);
    gemm_qkv<<<1536, 256, 0, stream>>>(Aq, Ak, Av, Wqb, Wkb, Wvb, bq, bk, bv,
                                       Qw, Kw, Vw);
    flash_attn<<<kB * kH * 16, 256, 0, stream>>>(Qw, Kw, Vw, Aq);  // ctx -> Aq
    gemm_one<0, float><<<512, 256, 0, stream>>>(Aq, Wob, bo, out);
  } else {
    // sequential fallback
    __bf16* Qw = (__bf16*)d_ws;
    __bf16* Kw = Qw + e;
    __bf16* Vw = Kw + e;
    __bf16* Ab = Vw + e;
    __bf16* Wb = Ab + e;

    const int actg = (int)(e / 8 / 256);
    const int wg = (int)(w / 8 / 256);
    cvt_f32_bf16<<<actg, 256, 0, stream>>>(query, Ab, (int)(e / 8));
    cvt_f32_bf16<<<wg, 256, 0, stream>>>(Wq, Wb, (int)(w / 8));
    gemm_one<1, __bf16><<<512, 256, 0, stream>>>(Ab, Wb, bq, Qw);
    cvt_f32_bf16<<<actg, 256, 0, stream>>>(key_, Ab, (int)(e / 8));
    cvt_f32_bf16<<<wg, 256, 0, stream>>>(Wk, Wb, (int)(w / 8));
    gemm_one<1, __bf16><<<512, 256, 0, stream>>>(Ab, Wb, bk, Kw);
    cvt_f32_bf16<<<actg, 256, 0, stream>>>(value, Ab, (int)(e / 8));
    cvt_f32_bf16<<<wg, 256, 0, stream>>>(Wv, Wb, (int)(w / 8));
    gemm_one<2, __bf16><<<512, 256, 0, stream>>>(Ab, Wb, bv, Vw);
    flash_attn<<<kB * kH * 16, 256, 0, stream>>>(Qw, Kw, Vw, Ab);
    cvt_f32_bf16<<<wg, 256, 0, stream>>>(Wo, Wb, (int)(w / 8));
    gemm_one<0, float><<<512, 256, 0, stream>>>(Ab, Wb, bo, out);
  }
}

// Round 5
// 346.623 us; speedup vs baseline: 1.1643x; 1.0525x over previous
//
#include <hip/hip_runtime.h>
#include <hip/hip_bf16.h>
#include <cstdint>
#include <cstddef>

// B=4, S=2048, D=1024, H=16, DK=64. Device I/O dtype: FLOAT32.
// Internal compute: bf16 MFMA with f32 accumulation.
static constexpr int kB = 4, kS = 2048, kD = 1024, kH = 16, kDK = 64;
static constexpr int kM = kB * kS;

typedef __attribute__((ext_vector_type(8))) __bf16 bf16x8;
typedef __attribute__((ext_vector_type(4))) float f32x4;

#define MFMA_BF16(a, b, c) __builtin_amdgcn_mfma_f32_16x16x32_bf16((a), (b), (c), 0, 0, 0)

#define GLDS16(gp, lp)                                                        \
  __builtin_amdgcn_global_load_lds(                                           \
      (__attribute__((address_space(1))) void*)(gp),                          \
      (__attribute__((address_space(3))) void*)(lp), 16, 0, 0)

// ---------------------------------------------------------------------------
// f32 -> bf16 converters
// ---------------------------------------------------------------------------
__device__ __forceinline__ bf16x8 cvt8(const float* s, int i) {
  const float4 a = ((const float4*)s)[i * 2 + 0];
  const float4 b = ((const float4*)s)[i * 2 + 1];
  bf16x8 o;
  o[0] = (__bf16)a.x; o[1] = (__bf16)a.y; o[2] = (__bf16)a.z; o[3] = (__bf16)a.w;
  o[4] = (__bf16)b.x; o[5] = (__bf16)b.y; o[6] = (__bf16)b.z; o[7] = (__bf16)b.w;
  return o;
}

__global__ __launch_bounds__(256) void cvt_f32_bf16(
    const float* __restrict__ src, __bf16* __restrict__ dst, int n8) {
  const int i = blockIdx.x * 256 + threadIdx.x;
  if (i >= n8) return;
  ((bf16x8*)dst)[i] = cvt8(src, i);
}

// all 7 input tensors in ONE launch: 3x4096 activation blocks + 4x512 weight
__global__ __launch_bounds__(256) void cvt_all(
    const float* __restrict__ q, const float* __restrict__ k,
    const float* __restrict__ v, const float* __restrict__ wq,
    const float* __restrict__ wk, const float* __restrict__ wv,
    const float* __restrict__ wo, __bf16* __restrict__ dq,
    __bf16* __restrict__ dk, __bf16* __restrict__ dv,
    __bf16* __restrict__ dwq, __bf16* __restrict__ dwk,
    __bf16* __restrict__ dwv, __bf16* __restrict__ dwo) {
  int bi = blockIdx.x;
  if (bi < 3 * 4096) {
    const int seg = bi >> 12;
    const int i = (bi & 4095) * 256 + threadIdx.x;
    const float* s = seg == 0 ? q : seg == 1 ? k : v;
    __bf16* d = seg == 0 ? dq : seg == 1 ? dk : dv;
    ((bf16x8*)d)[i] = cvt8(s, i);
  } else {
    bi -= 3 * 4096;
    const int seg = bi >> 9;
    const int i = (bi & 511) * 256 + threadIdx.x;
    const float* s = seg == 0 ? wq : seg == 1 ? wk : seg == 2 ? wv : wo;
    __bf16* d = seg == 0 ? dwq : seg == 1 ? dwk : seg == 2 ? dwv : dwo;
    ((bf16x8*)d)[i] = cvt8(s, i);
  }
}

// ---------------------------------------------------------------------------
// GEMM core: C[M,N] = A[M,K]*W[N,K]^T + bias; 128x128 tile, BK=64
// (proven round-0 structure: 2-barrier K-loop, XOR-granule LDS swizzle,
//  0 bank conflicts, ~87 us / MfmaUtil 24.7 on the QKV launch).
// mode 0: out[m*1024+n] ; mode 1: [b][h][s][dk] ; mode 2: [b][h][dk][s]
// ---------------------------------------------------------------------------
template <typename OutT>
__device__ __forceinline__ void gemm_core(
    const __bf16* __restrict__ A, const __bf16* __restrict__ W,
    const float* __restrict__ bias, OutT* __restrict__ out, int mode, int bid,
    __bf16* As, __bf16* Ws) {
  const int tid = threadIdx.x;
  const int wave = tid >> 6, lane = tid & 63;
  const int col = lane & 15, quad = lane >> 4;
  const int m0 = (bid & 63) * 128;
  const int n0 = (bid >> 6) * 128;
  const int wr = (wave & 1) * 64, wc = (wave >> 1) * 64;

  f32x4 acc[4][4] = {};

  int srow[4], sgo[4];
#pragma unroll
  for (int i = 0; i < 4; ++i) {
    const int s = i * 256 + tid;
    srow[i] = s >> 3;
    sgo[i] = (((s & 7) ^ ((s >> 3) & 7))) * 8;
  }
  const int g0 = ((quad) ^ (col & 7)) * 16;
  const int g1 = ((quad + 4) ^ (col & 7)) * 16;

  for (int k0 = 0; k0 < 1024; k0 += 64) {
#pragma unroll
    for (int i = 0; i < 4; ++i) {
      GLDS16(A + (size_t)(m0 + srow[i]) * 1024 + k0 + sgo[i],
             (char*)As + i * 4096 + wave * 1024);
      GLDS16(W + (size_t)(n0 + srow[i]) * 1024 + k0 + sgo[i],
             (char*)Ws + i * 4096 + wave * 1024);
    }
    __syncthreads();
#pragma unroll
    for (int h = 0; h < 2; ++h) {
      const int go = h ? g1 : g0;
      bf16x8 af[4], wf[4];
#pragma unroll
      for (int t = 0; t < 4; ++t) {
        af[t] = *(const bf16x8*)((const char*)As + (wr + t * 16 + col) * 128 + go);
        wf[t] = *(const bf16x8*)((const char*)Ws + (wc + t * 16 + col) * 128 + go);
      }
#pragma unroll
      for (int rt = 0; rt < 4; ++rt)
#pragma unroll
        for (int ct = 0; ct < 4; ++ct)
          acc[rt][ct] = MFMA_BF16(af[rt], wf[ct], acc[rt][ct]);
    }
    __syncthreads();
  }

#pragma unroll
  for (int ct = 0; ct < 4; ++ct) {
    const int n = n0 + wc + ct * 16 + col;
    const float bb = bias[n];
#pragma unroll
    for (int rt = 0; rt < 4; ++rt) {
#pragma unroll
      for (int r = 0; r < 4; ++r) {
        const int m = m0 + wr + rt * 16 + quad * 4 + r;
        const float v = acc[rt][ct][r] + bb;
        size_t idx;
        if (mode == 0) {
          idx = (size_t)m * 1024 + n;
        } else {
          const int b = m >> 11, s = m & 2047;
          const int h = n >> 6, dk = n & 63;
          if (mode == 1)
            idx = ((size_t)(b * 16 + h) * 2048 + s) * 64 + dk;
          else
            idx = ((size_t)(b * 16 + h) * 64 + dk) * 2048 + s;
        }
        out[idx] = (OutT)v;
      }
    }
  }
}

template <int MODE, typename OutT>
__global__ __launch_bounds__(256) void gemm_one(
    const __bf16* __restrict__ A, const __bf16* __restrict__ W,
    const float* __restrict__ bias, OutT* __restrict__ out) {
  __shared__ __align__(16) __bf16 As[128 * 64];
  __shared__ __align__(16) __bf16 Ws[128 * 64];
  gemm_core<OutT>(A, W, bias, out, MODE, blockIdx.x, As, Ws);
}

// Q/K/V projections fused into one 1536-block launch (round-0 proven)
__global__ __launch_bounds__(256) void gemm_qkv(
    const __bf16* __restrict__ Aq, const __bf16* __restrict__ Ak,
    const __bf16* __restrict__ Av, const __bf16* __restrict__ Wqb,
    const __bf16* __restrict__ Wkb, const __bf16* __restrict__ Wvb,
    const float* __restrict__ bq, const float* __restrict__ bk,
    const float* __restrict__ bv, __bf16* __restrict__ Qw,
    __bf16* __restrict__ Kw, __bf16* __restrict__ Vw) {
  __shared__ __align__(16) __bf16 As[128 * 64];
  __shared__ __align__(16) __bf16 Ws[128 * 64];
  const int seg = blockIdx.x >> 9;
  const int bid = blockIdx.x & 511;
  const __bf16* A = seg == 0 ? Aq : seg == 1 ? Ak : Av;
  const __bf16* W = seg == 0 ? Wqb : seg == 1 ? Wkb : Wvb;
  const float* bias = seg == 0 ? bq : seg == 1 ? bk : bv;
  __bf16* out = seg == 0 ? Qw : seg == 1 ? Kw : Vw;
  gemm_core<__bf16>(A, W, bias, out, seg == 2 ? 2 : 1, bid, As, Ws);
}

// ---------------------------------------------------------------------------
// Causal flash attention — round 5.
// Keep counted-vmcnt pipelined staging (round-4 win: staging latency hidden)
// but drop the double buffer to reclaim 4 blocks/CU (round-4 loss: LDS 51200
// -> 3 blocks/CU + 1024-block grid packed into 1.33 resident rounds).
// Single K/V buffers, stage split across the body:
//   entry:  vmcnt(2)  [K(c) landed, issued ~half-body ago; V(c) in flight]
//           barrier   [all waves' K(c) writes visible]
//   QK MFMAs (read Ks)
//   barrier [K WAR: all waves done reading Ks] -> stage K(c+1)
//   exp / P writes (per-wave Pb, intra-wave only)
//   vmcnt(2) [V(c) landed, issued a full body ago; leaves K(c+1) in flight]
//           barrier   [all waves' V(c) writes visible]
//   P reads + PV MFMAs + lacc (read Vs)
//   barrier [V WAR: all waves done reading Vs] -> stage V(c+1)
// Every vmcnt wait precedes a barrier that precedes the cross-wave reads
// (per-wave vmcnt only covers that wave's own GLDS writes).
// LDS = 8192(K) + 8192(V) + 18432(P) = 34816 -> 4 blocks/CU, 1024/1024 slots.
// Block order pair-major: bh = idx&63 -> all 16 pair-blocks of a bh land on
// one XCD (round-robin dispatch), K/V working set/XCD = 8 bh = 4 MB ~ L2;
// longest blocks (pair 0, 32 bodies) launch first.
// ---------------------------------------------------------------------------
__global__ __launch_bounds__(256, 4) void flash_attn(
    const __bf16* __restrict__ Q, const __bf16* __restrict__ K,
    const __bf16* __restrict__ Vt, __bf16* __restrict__ ctx) {
  __shared__ __align__(16) __bf16 Ks[64 * 64];
  __shared__ __align__(16) __bf16 Vs[64 * 64];
  __shared__ __align__(16) __bf16 Pb[4][2][16 * 72];

  const int tid = threadIdx.x;
  const int wave = tid >> 6, lane = tid & 63;
  const int col = lane & 15, quad = lane >> 4;
  const int bh = blockIdx.x & 63;    // pair-major order
  const int pair = blockIdx.x >> 6;
  const int b = bh >> 4, h = bh & 15;
  const int t_lo = pair, t_hi = 31 - pair;
  const int q0f[2] = {t_lo * 64 + wave * 16, t_hi * 64 + wave * 16};

  constexpr float SCL = 0.18033688011112042f;  // (1/8) * log2(e)

  bf16x8 qf[2][2];
#pragma unroll
  for (int f = 0; f < 2; ++f) {
    const __bf16* Qp = Q + ((size_t)bh * kS + q0f[f] + col) * 64 + quad * 8;
    qf[f][0] = *(const bf16x8*)Qp;
    qf[f][1] = *(const bf16x8*)(Qp + 32);
  }

  f32x4 o[2][4] = {};
  f32x4 lacc[2] = {};
  bf16x8 ones;
#pragma unroll
  for (int i = 0; i < 8; ++i) ones[i] = (__bf16)1.0f;

  const __bf16* Kg = K + (size_t)bh * kS * 64;
  const __bf16* Vg = Vt + (size_t)bh * 64 * kS;

  const int row0 = tid >> 3, g0 = (tid & 7) ^ (row0 & 7);
  const int row1 = (256 + tid) >> 3, g1 = (tid & 7) ^ (row1 & 7);

  const int fgoff0 = ((quad) ^ (col & 7)) * 16;
  const int fgoff1 = ((quad + 4) ^ (col & 7)) * 16;
  const int maskbase = wave * 16 + quad * 4;

  __bf16* Pw0 = &Pb[wave][0][0];
  __bf16* Pw1 = &Pb[wave][1][0];
  const __bf16* Pr0 = Pw0 + col * 72 + quad * 8;
  const __bf16* Pr1 = Pw1 + col * 72 + quad * 8;

  auto stageK = [&](int c) {
    char* KsB = (char*)Ks + wave * 1024;
    GLDS16(Kg + (size_t)(c * 64 + row0) * 64 + g0 * 8, KsB);
    GLDS16(Kg + (size_t)(c * 64 + row1) * 64 + g1 * 8, KsB + 4096);
  };
  auto stageV = [&](int c) {
    char* VsB = (char*)Vs + wave * 1024;
    GLDS16(Vg + (size_t)row0 * kS + c * 64 + g0 * 8, VsB);
    GLDS16(Vg + (size_t)row1 * kS + c * 64 + g1 * 8, VsB + 4096);
  };

  auto body = [&](int c, bool lo, bool d0, bool d1, bool stage_next) {
    // K(c) landed? (K issued before V -> vmcnt(2) leaves V(c) in flight)
    asm volatile("s_waitcnt vmcnt(2)" ::: "memory");
    __builtin_amdgcn_s_barrier();
    asm volatile("" ::: "memory");

    f32x4 s[2][4];
#pragma unroll
    for (int kt = 0; kt < 4; ++kt) {
      const char* kp = (const char*)Ks + (kt * 16 + col) * 128;
      const bf16x8 kf0 = *(const bf16x8*)(kp + fgoff0);
      const bf16x8 kf1 = *(const bf16x8*)(kp + fgoff1);
      f32x4 z = {};
      s[1][kt] = MFMA_BF16(qf[1][1], kf1, MFMA_BF16(qf[1][0], kf0, z));
      if (lo) s[0][kt] = MFMA_BF16(qf[0][1], kf1, MFMA_BF16(qf[0][0], kf0, z));
    }

    __builtin_amdgcn_s_barrier();  // K WAR: all waves done reading Ks
    asm volatile("" ::: "memory");
    if (stage_next) stageK(c + 1);

#pragma unroll
    for (int kt = 0; kt < 4; ++kt) {
#pragma unroll
      for (int r = 0; r < 4; ++r) {
        float pv1 = __builtin_amdgcn_exp2f(s[1][kt][r] * SCL);
        if (d1 && (kt * 16 + col > maskbase + r)) pv1 = 0.0f;
        Pw1[(quad * 4 + r) * 72 + kt * 16 + col] = (__bf16)pv1;
        if (lo) {
          float pv0 = __builtin_amdgcn_exp2f(s[0][kt][r] * SCL);
          if (d0 && (kt * 16 + col > maskbase + r)) pv0 = 0.0f;
          Pw0[(quad * 4 + r) * 72 + kt * 16 + col] = (__bf16)pv0;
        }
      }
    }
    __threadfence_block();

    // V(c) landed? (leaves K(c+1) in flight when staged)
    if (stage_next)
      asm volatile("s_waitcnt vmcnt(2)" ::: "memory");
    else
      asm volatile("s_waitcnt vmcnt(0)" ::: "memory");
    __builtin_amdgcn_s_barrier();
    asm volatile("" ::: "memory");

    const bf16x8 pf1a = *(const bf16x8*)Pr1;
    const bf16x8 pf1b = *(const bf16x8*)(Pr1 + 32);
    bf16x8 pf0a = {}, pf0b = {};
    if (lo) {
      pf0a = *(const bf16x8*)Pr0;
      pf0b = *(const bf16x8*)(Pr0 + 32);
    }
#pragma unroll
    for (int dt = 0; dt < 4; ++dt) {
      const char* vp = (const char*)Vs + (dt * 16 + col) * 128;
      const bf16x8 vf0 = *(const bf16x8*)(vp + fgoff0);
      const bf16x8 vf1 = *(const bf16x8*)(vp + fgoff1);
      o[1][dt] = MFMA_BF16(pf1b, vf1, MFMA_BF16(pf1a, vf0, o[1][dt]));
      if (lo) o[0][dt] = MFMA_BF16(pf0b, vf1, MFMA_BF16(pf0a, vf0, o[0][dt]));
    }
    lacc[1] = MFMA_BF16(pf1b, ones, MFMA_BF16(pf1a, ones, lacc[1]));
    if (lo) lacc[0] = MFMA_BF16(pf0b, ones, MFMA_BF16(pf0a, ones, lacc[0]));

    __builtin_amdgcn_s_barrier();  // V WAR: all waves done reading Vs
    asm volatile("" ::: "memory");
    if (stage_next) stageV(c + 1);
  };

  stageK(0);
  stageV(0);
  for (int c = 0; c <= t_lo; ++c) body(c, true, c == t_lo, false, c < t_hi);
  for (int c = t_lo + 1; c <= t_hi; ++c)
    body(c, false, false, c == t_hi, c < t_hi);

#pragma unroll
  for (int f = 0; f < 2; ++f) {
#pragma unroll
    for (int r = 0; r < 4; ++r) {
      const float inv = 1.0f / lacc[f][r];
      const int srow = q0f[f] + quad * 4 + r;
      __bf16* cp = ctx + ((size_t)b * kS + srow) * kD + h * 64 + col;
#pragma unroll
      for (int dt = 0; dt < 4; ++dt)
        cp[dt * 16] = (__bf16)(o[f][dt][r] * inv);
    }
  }
}

// ---------------------------------------------------------------------------
extern "C" void kernel_launch(void* const* d_in, const int* in_sizes, int n_in,
                              void* d_out, int out_size, void* d_ws, size_t ws_size,
                              hipStream_t stream) {
  const float* query = (const float*)d_in[0];
  const float* key_  = (const float*)d_in[1];
  const float* value = (const float*)d_in[2];
  const float* Wq = (const float*)d_in[4];
  const float* bq = (const float*)d_in[5];
  const float* Wk = (const float*)d_in[6];
  const float* bk = (const float*)d_in[7];
  const float* Wv = (const float*)d_in[8];
  const float* bv = (const float*)d_in[9];
  const float* Wo = (const float*)d_in[10];
  const float* bo = (const float*)d_in[11];

  const size_t e = (size_t)kM * kD;       // 8,388,608
  const size_t w = (size_t)kD * kD;       // 1,048,576
  float* out = (float*)d_out;

  const size_t REQ = (6 * e + 4 * w) * sizeof(__bf16);  // ~109 MB

  if (ws_size >= REQ) {
    // fused path
    __bf16* Qw  = (__bf16*)d_ws;
    __bf16* Kw  = Qw + e;
    __bf16* Vw  = Kw + e;     // [B,H,64,S]
    __bf16* Aq  = Vw + e;     // reused as ctx after gemm_qkv
    __bf16* Ak  = Aq + e;
    __bf16* Av  = Ak + e;
    __bf16* Wqb = Av + e;
    __bf16* Wkb = Wqb + w;
    __bf16* Wvb = Wkb + w;
    __bf16* Wob = Wvb + w;

    cvt_all<<<3 * 4096 + 4 * 512, 256, 0, stream>>>(
        query, key_, value, Wq, Wk, Wv, Wo, Aq, Ak, Av, Wqb, Wkb, Wvb, Wob);
    gemm_qkv<<<1536, 256, 0, stream>>>(Aq, Ak, Av, Wqb, Wkb, Wvb, bq, bk, bv,
                                       Qw, Kw, Vw);
    flash_attn<<<kB * kH * 16, 256, 0, stream>>>(Qw, Kw, Vw, Aq);  // ctx -> Aq
    gemm_one<0, float><<<512, 256, 0, stream>>>(Aq, Wob, bo, out);
  } else {
    // sequential fallback
    __bf16* Qw = (__bf16*)d_ws;
    __bf16* Kw = Qw + e;
    __bf16* Vw = Kw + e;
    __bf16* Ab = Vw + e;
    __bf16* Wb = Ab + e;

    const int actg = (int)(e / 8 / 256);
    const int wg = (int)(w / 8 / 256);
    cvt_f32_bf16<<<actg, 256, 0, stream>>>(query, Ab, (int)(e / 8));
    cvt_f32_bf16<<<wg, 256, 0, stream>>>(Wq, Wb, (int)(w / 8));
    gemm_one<1, __bf16><<<512, 256, 0, stream>>>(Ab, Wb, bq, Qw);
    cvt_f32_bf16<<<actg, 256, 0, stream>>>(key_, Ab, (int)(e / 8));
    cvt_f32_bf16<<<wg, 256, 0, stream>>>(Wk, Wb, (int)(w / 8));
    gemm_one<1, __bf16><<<512, 256, 0, stream>>>(Ab, Wb, bk, Kw);
    cvt_f32_bf16<<<actg, 256, 0, stream>>>(value, Ab, (int)(e / 8));
    cvt_f32_bf16<<<wg, 256, 0, stream>>>(Wv, Wb, (int)(w / 8));
    gemm_one<2, __bf16><<<512, 256, 0, stream>>>(Ab, Wb, bv, Vw);
    flash_attn<<<kB * kH * 16, 256, 0, stream>>>(Qw, Kw, Vw, Ab);
    cvt_f32_bf16<<<wg, 256, 0, stream>>>(Wo, Wb, (int)(w / 8));
    gemm_one<0, float><<<512, 256, 0, stream>>>(Ab, Wb, bo, out);
  }
}